// Round 9
// baseline (80.354 us; speedup 1.0000x reference)
//
#include <hip/hip_runtime.h>
#include <hip/hip_bf16.h>

#define NROWS 8192
#define DDIM  256
#define BM 128
#define BN 128
#define BK 64

typedef __attribute__((ext_vector_type(4))) float f32x4;
typedef __attribute__((ext_vector_type(8))) short bf16x8;
typedef __attribute__((ext_vector_type(4))) short short4v;

__device__ inline short f2bf(float f) {
    union { float f; unsigned u; } c; c.f = f;
    unsigned u = c.u;
    u += 0x7fffu + ((u >> 16) & 1u);   // round-to-nearest-even
    return (short)(u >> 16);
}

// ---------------- pre-pass: f32 -> bf16 convert + row norms -----------------
__global__ __launch_bounds__(256) void convert_norms_kernel(
    const float* __restrict__ x, const float* __restrict__ y,
    short* __restrict__ xb, short* __restrict__ yb,
    float* __restrict__ xsq, float* __restrict__ ysq) {
    int row  = blockIdx.x * 4 + (threadIdx.x >> 6);
    int lane = threadIdx.x & 63;
    const float* src; short* dstb; float* dstn; int r;
    if (row < NROWS) { r = row;        src = x + (size_t)r * DDIM; dstb = xb + (size_t)r * DDIM; dstn = xsq; }
    else             { r = row - NROWS; src = y + (size_t)r * DDIM; dstb = yb + (size_t)r * DDIM; dstn = ysq; }
    f32x4 v = __builtin_nontemporal_load(&((const f32x4*)src)[lane]);  // read-once
    short4v o;
    #pragma unroll
    for (int j = 0; j < 4; ++j) o[j] = f2bf(v[j]);
    ((short4v*)dstb)[lane] = o;                     // re-read by GEMM: keep cached
    float s = v[0]*v[0] + v[1]*v[1] + v[2]*v[2] + v[3]*v[3];
    #pragma unroll
    for (int off = 32; off > 0; off >>= 1) s += __shfl_xor(s, off, 64);
    if (lane == 0) dstn[r] = s;
}

// ---- main GEMM: R4 K-loop + hashed start-stagger + swapped dwordx4 epilogue
__global__ __launch_bounds__(256) void rbf_gemm_bf16_kernel(
    const char* __restrict__ Xb, const char* __restrict__ Yb,
    const float* __restrict__ xsq, const float* __restrict__ ysq,
    float* __restrict__ out) {
    __shared__ char lds[2 * BM * BK * 2];   // 32 KB: As | Bs
    char* As = lds;
    char* Bs = lds + BM * BK * 2;

    const int tid  = threadIdx.x;
    const int lane = tid & 63;
    const int wid  = tid >> 6;

    // De-phase blocks (theory: chip-wide phase-sync makes the store stream
    // bursty; HBM write pipe idles during K-loop phases). hash(bid)&3 x ~1us.
    const int bid = blockIdx.x;
    {
        const unsigned h = (unsigned)bid * 2654435761u;
        const int d = (h >> 28) & 3;
        for (int i = 0; i < d; ++i) __builtin_amdgcn_s_sleep(38);  // ~2432 cyc each
    }

    // T1 XCD-bijective swizzle: 4096 blocks = 8 XCDs x (32 by x 16 bx).
    const int xcd = bid & 7;
    const int c   = bid >> 3;
    const int by  = (xcd >> 2) * 32 + (c >> 4);
    const int bx  = (xcd & 3)  * 16 + (c & 15);
    const int brow = by * BM;
    const int bcol = bx * BN;
    const int wr = (wid >> 1) * 64;
    const int wc = (wid & 1) * 64;

    // Pre-swizzled per-lane global source addresses (rule #21; R2/R4-verified).
    const char* aS[4]; const char* bS[4];
    #pragma unroll
    for (int i = 0; i < 4; ++i) {
        const int q    = i * 4096 + tid * 16;       // linear LDS byte pos
        const int row  = q >> 7;                    // 128 B per tile row
        const int colb = q & 127;
        const int sc   = colb ^ ((row & 7) << 4);   // inverse swizzle (involution)
        aS[i] = Xb + (size_t)(brow + row) * 512 + sc;
        bS[i] = Yb + (size_t)(bcol + row) * 512 + sc;
    }

    f32x4 acc[4][4] = {};

    for (int ks = 0; ks < DDIM / BK; ++ks) {
        #pragma unroll
        for (int i = 0; i < 4; ++i) {
            __builtin_amdgcn_global_load_lds(
                (const __attribute__((address_space(1))) void*)(aS[i] + ks * 128),
                (__attribute__((address_space(3))) void*)(As + i * 4096 + wid * 1024),
                16, 0, 0);
            __builtin_amdgcn_global_load_lds(
                (const __attribute__((address_space(1))) void*)(bS[i] + ks * 128),
                (__attribute__((address_space(3))) void*)(Bs + i * 4096 + wid * 1024),
                16, 0, 0);
        }
        __syncthreads();

        #pragma unroll
        for (int kk = 0; kk < 2; ++kk) {
            const int kb = kk * 64 + ((lane >> 4) << 4);
            bf16x8 af[4], bf[4];
            #pragma unroll
            for (int m = 0; m < 4; ++m) {
                const int r = wr + m * 16 + (lane & 15);
                af[m] = *(const bf16x8*)(As + r * 128 + (kb ^ ((r & 7) << 4)));
            }
            #pragma unroll
            for (int n = 0; n < 4; ++n) {
                const int cc = wc + n * 16 + (lane & 15);
                bf[n] = *(const bf16x8*)(Bs + cc * 128 + (kb ^ ((cc & 7) << 4)));
            }
            #pragma unroll
            for (int m = 0; m < 4; ++m)
                #pragma unroll
                for (int n = 0; n < 4; ++n)
                    acc[m][n] = __builtin_amdgcn_mfma_f32_16x16x32_bf16(
                        bf[n], af[m], acc[m][n], 0, 0, 0);   // swapped (R5-R8 verified)
        }
        __syncthreads();
    }

    // Epilogue (swapped-D layout, R5-R8 verified): D col(lane&15) = X-row,
    // 4 regs = 4 consecutive Y-cols -> 16 dwordx4 stores (64-B row segments).
    #pragma unroll
    for (int m = 0; m < 4; ++m) {
        const int R  = brow + wr + m * 16 + (lane & 15);
        const float xsv = xsq[R];
        #pragma unroll
        for (int n = 0; n < 4; ++n) {
            const int C = bcol + wc + n * 16 + ((lane >> 4) << 2);
            const f32x4 ysv = *(const f32x4*)&ysq[C];
            f32x4 v;
            #pragma unroll
            for (int j = 0; j < 4; ++j)
                v[j] = __expf(2.0f * acc[m][n][j] - xsv - ysv[j]);
            *(f32x4*)&out[(size_t)R * NROWS + C] = v;
        }
    }
}

// ---------------- fallback (small ws): f32 reg-staging GEMM -----------------
__global__ __launch_bounds__(256) void row_norms_kernel(
    const float* __restrict__ x, const float* __restrict__ y,
    float* __restrict__ sq) {
    int row  = blockIdx.x * 4 + (threadIdx.x >> 6);
    int lane = threadIdx.x & 63;
    const float* src = (row < NROWS) ? (x + (size_t)row * DDIM)
                                     : (y + (size_t)(row - NROWS) * DDIM);
    f32x4 v = ((const f32x4*)src)[lane];
    float s = v[0]*v[0] + v[1]*v[1] + v[2]*v[2] + v[3]*v[3];
    #pragma unroll
    for (int off = 32; off > 0; off >>= 1) s += __shfl_xor(s, off, 64);
    if (lane == 0) sq[row] = s;
}

__global__ __launch_bounds__(256) void rbf_gemm_f32_kernel(
    const float* __restrict__ X, const float* __restrict__ Y,
    const float* __restrict__ xsq, const float* __restrict__ ysq,
    float* __restrict__ out) {
    __shared__ char lds[2 * BM * 64 * 2];
    char* As = lds;
    char* Bs = lds + BM * 64 * 2;
    const int tid  = threadIdx.x;
    const int lane = tid & 63;
    const int wid  = tid >> 6;
    const int brow = blockIdx.y * BM;
    const int bcol = blockIdx.x * BN;
    const int wr = (wid >> 1) * 64;
    const int wc = (wid & 1) * 64;
    const int srow  = tid >> 1;
    const int shalf = tid & 1;
    const float* aptr = X + (size_t)(brow + srow) * DDIM + shalf * 32;
    const float* bptr = Y + (size_t)(bcol + srow) * DDIM + shalf * 32;
    const int swz = (srow & 7) << 4;
    f32x4 acc[4][4] = {};
    for (int ks = 0; ks < DDIM / 64; ++ks) {
        __syncthreads();
        #pragma unroll
        for (int i = 0; i < 4; ++i) {
            f32x4 a0 = ((const f32x4*)(aptr + ks * 64))[2*i];
            f32x4 a1 = ((const f32x4*)(aptr + ks * 64))[2*i + 1];
            f32x4 b0 = ((const f32x4*)(bptr + ks * 64))[2*i];
            f32x4 b1 = ((const f32x4*)(bptr + ks * 64))[2*i + 1];
            bf16x8 av, bv;
            #pragma unroll
            for (int j = 0; j < 4; ++j) {
                av[j]   = f2bf(a0[j]);  av[4+j] = f2bf(a1[j]);
                bv[j]   = f2bf(b0[j]);  bv[4+j] = f2bf(b1[j]);
            }
            const int cb = shalf * 64 + i * 16;
            *(bf16x8*)(As + srow * 128 + (cb ^ swz)) = av;
            *(bf16x8*)(Bs + srow * 128 + (cb ^ swz)) = bv;
        }
        __syncthreads();
        #pragma unroll
        for (int kk = 0; kk < 2; ++kk) {
            const int kb = kk * 64 + ((lane >> 4) << 4);
            bf16x8 af[4], bf[4];
            #pragma unroll
            for (int m = 0; m < 4; ++m) {
                const int r = wr + m * 16 + (lane & 15);
                af[m] = *(const bf16x8*)(As + r * 128 + (kb ^ ((r & 7) << 4)));
            }
            #pragma unroll
            for (int n = 0; n < 4; ++n) {
                const int cc = wc + n * 16 + (lane & 15);
                bf[n] = *(const bf16x8*)(Bs + cc * 128 + (kb ^ ((cc & 7) << 4)));
            }
            #pragma unroll
            for (int m = 0; m < 4; ++m)
                #pragma unroll
                for (int n = 0; n < 4; ++n)
                    acc[m][n] = __builtin_amdgcn_mfma_f32_16x16x32_bf16(
                        af[m], bf[n], acc[m][n], 0, 0, 0);
        }
    }
    const int r0 = brow + wr + ((lane >> 4) << 2);
    const int c0 = bcol + wc + (lane & 15);
    float xs[4][4];
    #pragma unroll
    for (int m = 0; m < 4; ++m)
        #pragma unroll
        for (int j = 0; j < 4; ++j)
            xs[m][j] = xsq[r0 + m * 16 + j];
    #pragma unroll
    for (int n = 0; n < 4; ++n) {
        const float ys = ysq[c0 + n * 16];
        #pragma unroll
        for (int m = 0; m < 4; ++m) {
            #pragma unroll
            for (int j = 0; j < 4; ++j) {
                const int row = r0 + m * 16 + j;
                const float v = __expf(2.0f * acc[m][n][j] - xs[m][j] - ys);
                out[(size_t)row * NROWS + c0 + n * 16] = v;
            }
        }
    }
}

extern "C" void kernel_launch(void* const* d_in, const int* in_sizes, int n_in,
                              void* d_out, int out_size, void* d_ws, size_t ws_size,
                              hipStream_t stream) {
    const float* x = (const float*)d_in[0];
    const float* y = (const float*)d_in[1];
    float* out = (float*)d_out;

    const size_t xb_bytes = (size_t)NROWS * DDIM * 2;         // 4 MB
    const size_t needed   = 2 * xb_bytes + 2 * NROWS * 4;     // + norms

    if (ws_size >= needed) {
        char*  ws  = (char*)d_ws;
        short* xb  = (short*)ws;
        short* yb  = (short*)(ws + xb_bytes);
        float* xsq = (float*)(ws + 2 * xb_bytes);
        float* ysq = xsq + NROWS;
        convert_norms_kernel<<<dim3(2 * NROWS / 4), dim3(256), 0, stream>>>(
            x, y, xb, yb, xsq, ysq);
        rbf_gemm_bf16_kernel<<<dim3(4096), dim3(256), 0, stream>>>(
            (const char*)xb, (const char*)yb, xsq, ysq, out);
    } else {
        float* sq = (float*)d_ws;
        row_norms_kernel<<<dim3(2 * NROWS / 4), dim3(256), 0, stream>>>(x, y, sq);
        rbf_gemm_f32_kernel<<<dim3(NROWS / BN, NROWS / BM), dim3(256), 0, stream>>>(
            x, y, sq, sq + NROWS, out);
    }
}

// Round 10
// 67.001 us; speedup vs baseline: 1.1993x; 1.1993x over previous
//
#include <hip/hip_runtime.h>
#include <hip/hip_bf16.h>

#define NROWS 8192
#define DDIM  256
#define BM 128
#define BN 128
#define BK 64

typedef __attribute__((ext_vector_type(4))) float f32x4;
typedef __attribute__((ext_vector_type(8))) short bf16x8;
typedef __attribute__((ext_vector_type(4))) short short4v;

__device__ inline short f2bf(float f) {
    union { float f; unsigned u; } c; c.f = f;
    unsigned u = c.u;
    u += 0x7fffu + ((u >> 16) & 1u);   // round-to-nearest-even
    return (short)(u >> 16);
}

// ---------------- pre-pass: f32 -> bf16 convert + row norms -----------------
// One wave per row; rows [0,8192) -> x, [8192,16384) -> y.
__global__ __launch_bounds__(256) void convert_norms_kernel(
    const float* __restrict__ x, const float* __restrict__ y,
    short* __restrict__ xb, short* __restrict__ yb,
    float* __restrict__ xsq, float* __restrict__ ysq) {
    int row  = blockIdx.x * 4 + (threadIdx.x >> 6);
    int lane = threadIdx.x & 63;
    const float* src; short* dstb; float* dstn; int r;
    if (row < NROWS) { r = row;        src = x + (size_t)r * DDIM; dstb = xb + (size_t)r * DDIM; dstn = xsq; }
    else             { r = row - NROWS; src = y + (size_t)r * DDIM; dstb = yb + (size_t)r * DDIM; dstn = ysq; }
    f32x4 v = __builtin_nontemporal_load(&((const f32x4*)src)[lane]);  // read-once
    short4v o;
    #pragma unroll
    for (int j = 0; j < 4; ++j) o[j] = f2bf(v[j]);
    ((short4v*)dstb)[lane] = o;                     // re-read by GEMM: keep cached
    float s = v[0]*v[0] + v[1]*v[1] + v[2]*v[2] + v[3]*v[3];
    #pragma unroll
    for (int off = 32; off > 0; off >>= 1) s += __shfl_xor(s, off, 64);
    if (lane == 0) dstn[r] = s;
}

// ---------------- main GEMM: bf16 inputs via global_load_lds ----------------
__global__ __launch_bounds__(256) void rbf_gemm_bf16_kernel(
    const char* __restrict__ Xb, const char* __restrict__ Yb,
    const float* __restrict__ xsq, const float* __restrict__ ysq,
    float* __restrict__ out) {
    __shared__ char lds[2 * BM * BK * 2];   // 32 KB: As | Bs
    char* As = lds;
    char* Bs = lds + BM * BK * 2;

    const int tid  = threadIdx.x;
    const int lane = tid & 63;
    const int wid  = tid >> 6;

    // T1: XCD-bijective swizzle. nwg = 4096 = 8 XCDs x 512 blocks.
    // Each XCD owns a 32(by) x 16(bx) super-tile: X-panel 2 MB + Y-panel 1 MB
    // bf16 -> L2-resident per XCD.
    const int bid = blockIdx.x;
    const int xcd = bid & 7;
    const int c   = bid >> 3;           // [0,512)
    const int by  = (xcd >> 2) * 32 + (c >> 4);
    const int bx  = (xcd & 3)  * 16 + (c & 15);
    const int brow = by * BM;
    const int bcol = bx * BN;
    const int wr = (wid >> 1) * 64;
    const int wc = (wid & 1) * 64;

    // Pre-swizzled per-lane global source addresses (rule #21: linear LDS dest,
    // inverse-swizzled source, swizzled read). Row stride in bf16 bytes = 512.
    const char* aS[4]; const char* bS[4];
    #pragma unroll
    for (int i = 0; i < 4; ++i) {
        const int q    = i * 4096 + tid * 16;       // linear LDS byte pos
        const int row  = q >> 7;                    // 128 B per tile row
        const int colb = q & 127;
        const int sc   = colb ^ ((row & 7) << 4);   // inverse swizzle (involution)
        aS[i] = Xb + (size_t)(brow + row) * 512 + sc;
        bS[i] = Yb + (size_t)(bcol + row) * 512 + sc;
    }

    f32x4 acc[4][4] = {};

    for (int ks = 0; ks < DDIM / BK; ++ks) {
        // stage 16 KB A + 16 KB B, 16 B/lane, wave-uniform LDS base
        #pragma unroll
        for (int i = 0; i < 4; ++i) {
            __builtin_amdgcn_global_load_lds(
                (const __attribute__((address_space(1))) void*)(aS[i] + ks * 128),
                (__attribute__((address_space(3))) void*)(As + i * 4096 + wid * 1024),
                16, 0, 0);
            __builtin_amdgcn_global_load_lds(
                (const __attribute__((address_space(1))) void*)(bS[i] + ks * 128),
                (__attribute__((address_space(3))) void*)(Bs + i * 4096 + wid * 1024),
                16, 0, 0);
        }
        __syncthreads();   // drains vmcnt(0) before barrier

        #pragma unroll
        for (int kk = 0; kk < 2; ++kk) {
            const int kb = kk * 64 + ((lane >> 4) << 4);
            bf16x8 af[4], bf[4];
            #pragma unroll
            for (int m = 0; m < 4; ++m) {
                const int r = wr + m * 16 + (lane & 15);
                af[m] = *(const bf16x8*)(As + r * 128 + (kb ^ ((r & 7) << 4)));
            }
            #pragma unroll
            for (int n = 0; n < 4; ++n) {
                const int cc = wc + n * 16 + (lane & 15);
                bf[n] = *(const bf16x8*)(Bs + cc * 128 + (kb ^ ((cc & 7) << 4)));
            }
            #pragma unroll
            for (int m = 0; m < 4; ++m)
                #pragma unroll
                for (int n = 0; n < 4; ++n)
                    acc[m][n] = __builtin_amdgcn_mfma_f32_16x16x32_bf16(
                        af[m], bf[n], acc[m][n], 0, 0, 0);
        }
        __syncthreads();
    }

    // Epilogue: C/D layout col=lane&15, row=(lane>>4)*4+reg  [m89-verified]
    // Plain stores (R3 post-mortem: nontemporal stores bypass the 256 MiB
    // memory-side Infinity Cache -> forced HBM rate; normal stream is faster).
    const int r0 = brow + wr + ((lane >> 4) << 2);
    const int c0 = bcol + wc + (lane & 15);
    float xs[4][4];
    #pragma unroll
    for (int m = 0; m < 4; ++m)
        #pragma unroll
        for (int j = 0; j < 4; ++j)
            xs[m][j] = xsq[r0 + m * 16 + j];
    #pragma unroll
    for (int n = 0; n < 4; ++n) {
        const float ys = ysq[c0 + n * 16];
        #pragma unroll
        for (int m = 0; m < 4; ++m) {
            #pragma unroll
            for (int j = 0; j < 4; ++j) {
                const int row = r0 + m * 16 + j;
                const float v = __expf(2.0f * acc[m][n][j] - xs[m][j] - ys);
                out[(size_t)row * NROWS + c0 + n * 16] = v;
            }
        }
    }
}

// ---------------- fallback (small ws): f32 reg-staging GEMM -----------------
__global__ __launch_bounds__(256) void row_norms_kernel(
    const float* __restrict__ x, const float* __restrict__ y,
    float* __restrict__ sq) {
    int row  = blockIdx.x * 4 + (threadIdx.x >> 6);
    int lane = threadIdx.x & 63;
    const float* src = (row < NROWS) ? (x + (size_t)row * DDIM)
                                     : (y + (size_t)(row - NROWS) * DDIM);
    f32x4 v = ((const f32x4*)src)[lane];
    float s = v[0]*v[0] + v[1]*v[1] + v[2]*v[2] + v[3]*v[3];
    #pragma unroll
    for (int off = 32; off > 0; off >>= 1) s += __shfl_xor(s, off, 64);
    if (lane == 0) sq[row] = s;
}

__global__ __launch_bounds__(256) void rbf_gemm_f32_kernel(
    const float* __restrict__ X, const float* __restrict__ Y,
    const float* __restrict__ xsq, const float* __restrict__ ysq,
    float* __restrict__ out) {
    __shared__ char lds[2 * BM * 64 * 2];
    char* As = lds;
    char* Bs = lds + BM * 64 * 2;
    const int tid  = threadIdx.x;
    const int lane = tid & 63;
    const int wid  = tid >> 6;
    const int brow = blockIdx.y * BM;
    const int bcol = blockIdx.x * BN;
    const int wr = (wid >> 1) * 64;
    const int wc = (wid & 1) * 64;
    const int srow  = tid >> 1;
    const int shalf = tid & 1;
    const float* aptr = X + (size_t)(brow + srow) * DDIM + shalf * 32;
    const float* bptr = Y + (size_t)(bcol + srow) * DDIM + shalf * 32;
    const int swz = (srow & 7) << 4;
    f32x4 acc[4][4] = {};
    for (int ks = 0; ks < DDIM / 64; ++ks) {
        __syncthreads();
        #pragma unroll
        for (int i = 0; i < 4; ++i) {
            f32x4 a0 = ((const f32x4*)(aptr + ks * 64))[2*i];
            f32x4 a1 = ((const f32x4*)(aptr + ks * 64))[2*i + 1];
            f32x4 b0 = ((const f32x4*)(bptr + ks * 64))[2*i];
            f32x4 b1 = ((const f32x4*)(bptr + ks * 64))[2*i + 1];
            bf16x8 av, bv;
            #pragma unroll
            for (int j = 0; j < 4; ++j) {
                av[j]   = f2bf(a0[j]);  av[4+j] = f2bf(a1[j]);
                bv[j]   = f2bf(b0[j]);  bv[4+j] = f2bf(b1[j]);
            }
            const int cb = shalf * 64 + i * 16;
            *(bf16x8*)(As + srow * 128 + (cb ^ swz)) = av;
            *(bf16x8*)(Bs + srow * 128 + (cb ^ swz)) = bv;
        }
        __syncthreads();
        #pragma unroll
        for (int kk = 0; kk < 2; ++kk) {
            const int kb = kk * 64 + ((lane >> 4) << 4);
            bf16x8 af[4], bf[4];
            #pragma unroll
            for (int m = 0; m < 4; ++m) {
                const int r = wr + m * 16 + (lane & 15);
                af[m] = *(const bf16x8*)(As + r * 128 + (kb ^ ((r & 7) << 4)));
            }
            #pragma unroll
            for (int n = 0; n < 4; ++n) {
                const int cc = wc + n * 16 + (lane & 15);
                bf[n] = *(const bf16x8*)(Bs + cc * 128 + (kb ^ ((cc & 7) << 4)));
            }
            #pragma unroll
            for (int m = 0; m < 4; ++m)
                #pragma unroll
                for (int n = 0; n < 4; ++n)
                    acc[m][n] = __builtin_amdgcn_mfma_f32_16x16x32_bf16(
                        af[m], bf[n], acc[m][n], 0, 0, 0);
        }
    }
    const int r0 = brow + wr + ((lane >> 4) << 2);
    const int c0 = bcol + wc + (lane & 15);
    float xs[4][4];
    #pragma unroll
    for (int m = 0; m < 4; ++m)
        #pragma unroll
        for (int j = 0; j < 4; ++j)
            xs[m][j] = xsq[r0 + m * 16 + j];
    #pragma unroll
    for (int n = 0; n < 4; ++n) {
        const float ys = ysq[c0 + n * 16];
        #pragma unroll
        for (int m = 0; m < 4; ++m) {
            #pragma unroll
            for (int j = 0; j < 4; ++j) {
                const int row = r0 + m * 16 + j;
                const float v = __expf(2.0f * acc[m][n][j] - xs[m][j] - ys);
                out[(size_t)row * NROWS + c0 + n * 16] = v;
            }
        }
    }
}

extern "C" void kernel_launch(void* const* d_in, const int* in_sizes, int n_in,
                              void* d_out, int out_size, void* d_ws, size_t ws_size,
                              hipStream_t stream) {
    const float* x = (const float*)d_in[0];
    const float* y = (const float*)d_in[1];
    float* out = (float*)d_out;

    const size_t xb_bytes = (size_t)NROWS * DDIM * 2;         // 4 MB
    const size_t needed   = 2 * xb_bytes + 2 * NROWS * 4;     // + norms

    if (ws_size >= needed) {
        char*  ws  = (char*)d_ws;
        short* xb  = (short*)ws;
        short* yb  = (short*)(ws + xb_bytes);
        float* xsq = (float*)(ws + 2 * xb_bytes);
        float* ysq = xsq + NROWS;
        convert_norms_kernel<<<dim3(2 * NROWS / 4), dim3(256), 0, stream>>>(
            x, y, xb, yb, xsq, ysq);
        rbf_gemm_bf16_kernel<<<dim3(4096), dim3(256), 0, stream>>>(
            (const char*)xb, (const char*)yb, xsq, ysq, out);
    } else {
        float* sq = (float*)d_ws;
        row_norms_kernel<<<dim3(2 * NROWS / 4), dim3(256), 0, stream>>>(x, y, sq);
        rbf_gemm_f32_kernel<<<dim3(NROWS / BN, NROWS / BM), dim3(256), 0, stream>>>(
            x, y, sq, sq + NROWS, out);
    }
}